// Round 10
// baseline (249.688 us; speedup 1.0000x reference)
//
#include <hip/hip_runtime.h>
#include <math.h>
#include <stdint.h>

// ---------------- problem constants ----------------
#define NROWS 48000
#define DIM   256
#define KCB   1024
#define GK    64
#define TM    128     // rows per k_dist item (4 waves x 2 sets x 16 rows)
#define NRT   375     // row tiles
#define NQ    4       // codebook quarters
#define NCHQ  16      // chunks of 16 codes per quarter (64 total / 4)
                      // ROUND-9 BUG: was 8 -> only codes 0..511 ever scanned
#define NIT   (NRT * NQ)   // 1500 work items
#define NBLK  512     // persistent blocks = 2/CU capacity

// ---------------- workspace byte offsets ----------------
#define WS_SCNT    0u         // int[1024]
#define WS_GSUM    4096u      // float[64]
#define WS_GCNT    4352u      // float[64]
#define WS_WORK    4608u      // int[1] work-stealing cursor
#define WS_ZERO_BYTES 4612u
#define WS_OFFS    4624u      // int[1024]
#define WS_CURS    8720u      // int[1024]
#define WS_ROWCODE 12816u     // int[48000]
#define WS_BUCKET  204816u    // int[48000]
#define WS_CBHI    396816u    // _Float16[1024*256] swizzled (524288 B)
#define WS_CBLO    921104u    // _Float16[1024*256] swizzled (524288 B)
#define WS_BEST    1445392u   // uint64[48000] atomicMax-merged argmax keys (384000 B)
#define WS_BEST_BYTES 384000u // total ws end: 1829392 < proven-safe 2.21 MB

// ---------------- output element offsets ----------------
#define OUT_SHAPE 12288000
#define OUT_GAIN  12550144
#define OUT_SNUM  12550208
#define OUT_GNUM  12551232

typedef _Float16 half8  __attribute__((ext_vector_type(8)));
typedef float    f32x4  __attribute__((ext_vector_type(4)));
typedef int      i32x4  __attribute__((ext_vector_type(4)));

typedef __attribute__((address_space(1))) void* gptr_t;
typedef __attribute__((address_space(3))) void* lptr_t;

// K0: split fp32 codebook into f16 hi/lo planes, pre-swizzled into a
// LANE-LINEAR fragment order so that global_load_lds (which writes LDS at
// wave-uniform-base + lane*16B) lands each lane's MFMA B-fragment exactly
// where the lane will ds_read it back (lane*16B within the fragment).
// dst(halfs) = ch*4096 + kk*512 + lane*8 + e, lane = lq*16 + lc,
// where code = ch*16+lc, k = kk*32 + lq*8 + e.
__global__ __launch_bounds__(256) void k_convert_cb(const float* __restrict__ cb,
                                                    _Float16* __restrict__ hi,
                                                    _Float16* __restrict__ lo) {
    int i = blockIdx.x * 256 + threadIdx.x;   // 262144 total
    float v = cb[i];
    int code = i >> 8, k = i & 255;
    int ch = code >> 4, lc = code & 15;
    int kk = k >> 5, lq = (k & 31) >> 3, e = k & 7;
    int lane = lq * 16 + lc;
    int dst = ch * 4096 + kk * 512 + lane * 8 + e;
    _Float16 h = (_Float16)v;
    hi[dst] = h;
    lo[dst] = (_Float16)(v - (float)h);
}

// K1: persistent work-stealing distance + argmax.
// Round-7's 750-block grid on a 512-slot capacity ran 2 rounds at 73%
// utilization (makespan 2T=84.5us). Round 8 proved counted-vmcnt is the
// wrong lever on this shallow loop (-9%). Here: 1500 quarter-codebook items
// (16 chunks each) pulled by 512 persistent blocks from an atomic cursor ->
// makespan ~2.93 item-rounds ~ 97% slot utilization. Items quarter-major so
// all CUs stream the same 256KB codebook slice (L2-hot); x re-reads hit L3.
// Per-row partial merged in-kernel via u64 atomicMax (key =
// monotone-float<<32 | ~code: max == larger dot, then smaller code —
// jnp.argmax tie-break). Inner K-loop identical to round 7 (LDS-DMA
// double-buffer + A-fragment asm pin).
__global__ __launch_bounds__(256, 2) void k_dist(
    const float* __restrict__ x,
    const _Float16* __restrict__ cbh, const _Float16* __restrict__ cbl,
    unsigned long long* __restrict__ ws_best, int* __restrict__ ws_work) {
    __shared__ alignas(16) _Float16 ldsB[2][2][4096];  // [buf][hi/lo][8 KB]
    __shared__ int shItem;

    const int tid = threadIdx.x;
    const int w = tid >> 6, lane = tid & 63;
    const int lc = lane & 15, lq = lane >> 4;

    for (;;) {
        if (tid == 0) shItem = atomicAdd(ws_work, 1);
        __syncthreads();
        const int item = shItem;     // uniform; next overwrite is behind the
        if (item >= NIT) break;      // K-loop barriers of this item
        const int q  = item / NRT;   // codebook quarter (quarter-major)
        const int rt = item - q * NRT;
        const int row0 = rt * TM;
        const int chbase = q * NCHQ;

        // ---- stage chunk chbase into LDS buf0 (DMA first, hide under A-load)
#pragma unroll
        for (int j = 0; j < 4; ++j) {
            int f = w * 4 + j;
            int plane = f >> 3, kk = f & 7;
            const char* srcb = plane ? (const char*)cbl : (const char*)cbh;
            const char* src = srcb + (size_t)chbase * 8192 + kk * 1024 + lane * 16;
            __builtin_amdgcn_global_load_lds((gptr_t)src,
                                             (lptr_t)&ldsB[0][plane][kk * 512],
                                             16, 0, 0);
        }

        // ---- load + convert A fragments: 2 sets of 16 rows per wave ----
        i32x4 afh[2][8], afl[2][8];
#pragma unroll
        for (int s = 0; s < 2; ++s) {
            const float* rp = x + (long)(row0 + w * 32 + s * 16 + lc) * DIM + lq * 8;
#pragma unroll
            for (int kk = 0; kk < 8; ++kk) {
                float4 v0 = *(const float4*)(rp + kk * 32);
                float4 v1 = *(const float4*)(rp + kk * 32 + 4);
                _Float16 h0 = (_Float16)v0.x, h1 = (_Float16)v0.y,
                         h2 = (_Float16)v0.z, h3 = (_Float16)v0.w;
                _Float16 h4 = (_Float16)v1.x, h5 = (_Float16)v1.y,
                         h6 = (_Float16)v1.z, h7 = (_Float16)v1.w;
                half8 hh = (half8){h0, h1, h2, h3, h4, h5, h6, h7};
                half8 ll = (half8){(_Float16)(v0.x - (float)h0), (_Float16)(v0.y - (float)h1),
                                   (_Float16)(v0.z - (float)h2), (_Float16)(v0.w - (float)h3),
                                   (_Float16)(v1.x - (float)h4), (_Float16)(v1.y - (float)h5),
                                   (_Float16)(v1.z - (float)h6), (_Float16)(v1.w - (float)h7)};
                afh[s][kk] = __builtin_bit_cast(i32x4, hh);
                afl[s][kk] = __builtin_bit_cast(i32x4, ll);
            }
        }

        // ---- PIN: opaque asm def keeps A-fragments register-resident
        // (round-7 fix: without it the compiler re-loads+re-converts x every
        //  chunk; VGPR=84 + 14MB scratch WRITE_SIZE was the signature)
#pragma unroll
        for (int s = 0; s < 2; ++s)
#pragma unroll
            for (int kk = 0; kk < 8; ++kk)
                asm volatile("" : "+v"(afh[s][kk]), "+v"(afl[s][kk]));

        float vmax[2][4];
        int   vidx[2][4];
#pragma unroll
        for (int s = 0; s < 2; ++s)
#pragma unroll
            for (int r = 0; r < 4; ++r) { vmax[s][r] = -1e30f; vidx[s][r] = 0; }

        __syncthreads();   // drains vmcnt: buf0 staged

        // ---- K-loop over this quarter's 16 chunks: 2-phase dbuf (round-7) ----
        int cur = 0;
        for (int ch = 0; ch < NCHQ; ++ch) {
            if (ch + 1 < NCHQ) {
#pragma unroll
                for (int j = 0; j < 4; ++j) {
                    int f = w * 4 + j;
                    int plane = f >> 3, kk = f & 7;
                    const char* srcb = plane ? (const char*)cbl : (const char*)cbh;
                    const char* src = srcb + (size_t)(chbase + ch + 1) * 8192 + kk * 1024 + lane * 16;
                    __builtin_amdgcn_global_load_lds((gptr_t)src,
                                                     (lptr_t)&ldsB[cur ^ 1][plane][kk * 512],
                                                     16, 0, 0);
                }
            }

            const _Float16* bH = &ldsB[cur][0][lane * 8];
            const _Float16* bL = &ldsB[cur][1][lane * 8];

            f32x4 a0[2], a1[2], a2[2];
#pragma unroll
            for (int s = 0; s < 2; ++s) {
                a0[s] = (f32x4){0, 0, 0, 0};
                a1[s] = (f32x4){0, 0, 0, 0};
                a2[s] = (f32x4){0, 0, 0, 0};
            }
#pragma unroll
            for (int kk = 0; kk < 8; ++kk) {
                half8 bh = *(const half8*)(bH + kk * 512);
                half8 bl = *(const half8*)(bL + kk * 512);
#pragma unroll
                for (int s = 0; s < 2; ++s) {
                    half8 ah = __builtin_bit_cast(half8, afh[s][kk]);
                    half8 al = __builtin_bit_cast(half8, afl[s][kk]);
                    a0[s] = __builtin_amdgcn_mfma_f32_16x16x32_f16(ah, bh, a0[s], 0, 0, 0);
                    a1[s] = __builtin_amdgcn_mfma_f32_16x16x32_f16(al, bh, a1[s], 0, 0, 0);
                    a2[s] = __builtin_amdgcn_mfma_f32_16x16x32_f16(ah, bl, a2[s], 0, 0, 0);
                }
            }
            int code = (chbase + ch) * 16 + lc;
#pragma unroll
            for (int s = 0; s < 2; ++s)
#pragma unroll
                for (int r = 0; r < 4; ++r) {
                    float dv = a0[s][r] + a1[s][r] + a2[s][r];
                    if (dv > vmax[s][r]) { vmax[s][r] = dv; vidx[s][r] = code; }
                }

            __syncthreads();   // drains DMA for next buf; syncs buffer swap
            cur ^= 1;
        }

        // ---- argmax reduce across the 16-lane col (lc) dimension ----
#pragma unroll
        for (int m = 1; m < 16; m <<= 1) {
#pragma unroll
            for (int s = 0; s < 2; ++s)
#pragma unroll
                for (int r = 0; r < 4; ++r) {
                    float ov = __shfl_xor(vmax[s][r], m, 64);
                    int   oi = __shfl_xor(vidx[s][r], m, 64);
                    if (ov > vmax[s][r] || (ov == vmax[s][r] && oi < vidx[s][r])) {
                        vmax[s][r] = ov; vidx[s][r] = oi;
                    }
                }
        }
        if (lc == 0) {
#pragma unroll
            for (int s = 0; s < 2; ++s)
#pragma unroll
                for (int r = 0; r < 4; ++r) {
                    int lrow = w * 32 + s * 16 + lq * 4 + r;
                    unsigned bits = __float_as_uint(vmax[s][r]);
                    unsigned eb = (bits & 0x80000000u) ? ~bits : (bits | 0x80000000u);
                    unsigned long long key =
                        ((unsigned long long)eb << 32) | (unsigned)(~(unsigned)vidx[s][r]);
                    atomicMax(ws_best + row0 + lrow, key);   // all real keys > 0
                }
        }
    }
}

// K1b: per-row gain quantization + stats + quantize output from the
// atomicMax-merged key (single read per row).
__global__ __launch_bounds__(256) void k_post(
    const float* __restrict__ cb, const float* __restrict__ gcb,
    const unsigned long long* __restrict__ ws_best,
    int* __restrict__ ws_scnt, float* __restrict__ ws_gsum,
    float* __restrict__ ws_gcnt, int* __restrict__ ws_rowcode,
    float* __restrict__ out_q) {
    __shared__ float gl[GK];
    __shared__ float shGs[GK];
    __shared__ float shGc[GK];
    __shared__ int   shInd[64];
    __shared__ float shGq[64];
    const int tid = threadIdx.x;
    const int row0 = blockIdx.x * 64;

    if (tid < GK) {
        gl[tid] = gcb[tid];
        shGs[tid] = 0.0f;
        shGc[tid] = 0.0f;
    }
    __syncthreads();

    if (tid < 64) {
        int row = row0 + tid;
        unsigned long long kb = ws_best[row];
        int code = (int)(~(unsigned)kb) & (KCB - 1);
        unsigned eb = (unsigned)(kb >> 32);
        unsigned fb = (eb & 0x80000000u) ? (eb & 0x7fffffffu) : ~eb;
        float gv = __uint_as_float(fb);
        float lg = logf(fmaxf(gv, 1e-5f));
        // gain argmin over 64 levels (strict < -> first min, == jnp.argmax tie-break)
        float bd = 1e30f;
        int gi = 0;
#pragma unroll
        for (int j = 0; j < GK; ++j) {
            float d = lg - gl[j];
            d = d * d;
            if (d < bd) { bd = d; gi = j; }
        }
        shInd[tid] = code;
        shGq[tid] = expf(gl[gi]);
        ws_rowcode[row] = code;
        atomicAdd(ws_scnt + code, 1);
        atomicAdd(shGs + gi, lg);
        atomicAdd(shGc + gi, 1.0f);
    }
    __syncthreads();
    if (tid < GK) {
        if (shGc[tid] != 0.0f) {
            atomicAdd(ws_gsum + tid, shGs[tid]);
            atomicAdd(ws_gcnt + tid, shGc[tid]);
        }
    }

    // ---- epilogue: quantize = exp(gain_q) * cb[code], 64 rows ----
    {
        float4* qv = (float4*)(out_q + (long)row0 * DIM);
#pragma unroll
        for (int it = 0; it < 16; ++it) {
            int idx = it * 256 + tid;       // 4096 float4s
            int r = idx >> 6, c4 = idx & 63;
            int code = shInd[r];
            float gq = shGq[r];
            const float4 cbv = *(const float4*)(cb + code * DIM + c4 * 4);
            float4 o;
            o.x = gq * cbv.x; o.y = gq * cbv.y; o.z = gq * cbv.z; o.w = gq * cbv.w;
            qv[idx] = o;
        }
    }
}

// K2a: exclusive prefix scan of code counts -> bucket offsets + cursors
__global__ __launch_bounds__(1024) void k_scan(const int* __restrict__ scnt,
                                               int* __restrict__ offs,
                                               int* __restrict__ curs) {
    int t = threadIdx.x;
    __shared__ int sc[1024];
    int my = scnt[t];
    sc[t] = my;
    __syncthreads();
    for (int d = 1; d < 1024; d <<= 1) {
        int v = (t >= d) ? sc[t - d] : 0;
        __syncthreads();
        sc[t] += v;
        __syncthreads();
    }
    int ex = sc[t] - my;
    offs[t] = ex;
    curs[t] = ex;
}

// K2b: scatter row ids into code-sorted buckets
__global__ __launch_bounds__(256) void k_scatter(const int* __restrict__ rowcode,
                                                 int* __restrict__ curs,
                                                 int* __restrict__ bucket) {
    int i = blockIdx.x * 256 + threadIdx.x;
    if (i < NROWS) {
        int code = rowcode[i];
        int pos = atomicAdd(curs + code, 1);
        bucket[pos] = i;
    }
}

// K2c: per-code column reduction of x + full shape/gain finalize
__global__ __launch_bounds__(256) void k_reduce(
    const float* __restrict__ x, const float* __restrict__ cb,
    const float* __restrict__ gcb, const float* __restrict__ snum,
    const float* __restrict__ gnum,
    const int* __restrict__ scnt, const int* __restrict__ offs,
    const int* __restrict__ bucket,
    const float* __restrict__ gsum, const float* __restrict__ gcnt,
    float* __restrict__ out) {
    int b = blockIdx.x, t = threadIdx.x;
    if (b < KCB) {
        int cnt = scnt[b], base = offs[b];
        float s = 0.0f;
        int i = 0;
        for (; i + 4 <= cnt; i += 4) {
            int r0 = bucket[base + i], r1 = bucket[base + i + 1];
            int r2 = bucket[base + i + 2], r3 = bucket[base + i + 3];
            float v0 = x[r0 * DIM + t], v1 = x[r1 * DIM + t];
            float v2 = x[r2 * DIM + t], v3 = x[r3 * DIM + t];
            s += v0 + v1 + v2 + v3;
        }
        for (; i < cnt; ++i) {
            int r = bucket[base + i];
            s += x[r * DIM + t];
        }
        __shared__ float red[4];
        int w = t >> 6;
        float v = s * s;
#pragma unroll
        for (int m = 32; m; m >>= 1) v += __shfl_xor(v, m, 64);
        if ((t & 63) == 0) red[w] = v;
        __syncthreads();
        float tot = red[0] + red[1] + red[2] + red[3];
        float sn = s / fmaxf(sqrtf(tot), 1e-5f);
        float u = cb[b * DIM + t] * 0.99f + 0.01f * sn;
        __syncthreads();
        v = u * u;
#pragma unroll
        for (int m = 32; m; m >>= 1) v += __shfl_xor(v, m, 64);
        if ((t & 63) == 0) red[w] = v;
        __syncthreads();
        tot = red[0] + red[1] + red[2] + red[3];
        out[OUT_SHAPE + b * DIM + t] = u / fmaxf(sqrtf(tot), 1e-12f);
        if (t == 0) out[OUT_SNUM + b] = snum[b] * 0.99f + 0.01f * (float)cnt;
    } else if (t < GK) {
        float cnt = gcnt[t];
        float gn  = gsum[t] / fmaxf(cnt, 1e-5f);
        out[OUT_GAIN + t] = gcb[t] * 0.99f + 0.01f * gn;
        out[OUT_GNUM + t] = gnum[t] * 0.99f + 0.01f * cnt;
    }
}

extern "C" void kernel_launch(void* const* d_in, const int* in_sizes, int n_in,
                              void* d_out, int out_size, void* d_ws, size_t ws_size,
                              hipStream_t stream) {
    const float* x    = (const float*)d_in[0];
    const float* cb   = (const float*)d_in[1];
    const float* gcb  = (const float*)d_in[2];
    const float* snum = (const float*)d_in[3];
    const float* gnum = (const float*)d_in[4];
    float* out = (float*)d_out;
    char*  ws  = (char*)d_ws;
    int*   ws_scnt    = (int*)(ws + WS_SCNT);
    float* ws_gsum    = (float*)(ws + WS_GSUM);
    float* ws_gcnt    = (float*)(ws + WS_GCNT);
    int*   ws_work    = (int*)(ws + WS_WORK);
    int*   ws_offs    = (int*)(ws + WS_OFFS);
    int*   ws_curs    = (int*)(ws + WS_CURS);
    int*   ws_rowcode = (int*)(ws + WS_ROWCODE);
    int*   ws_bucket  = (int*)(ws + WS_BUCKET);
    _Float16* cbh = (_Float16*)(ws + WS_CBHI);
    _Float16* cbl = (_Float16*)(ws + WS_CBLO);
    unsigned long long* ws_best = (unsigned long long*)(ws + WS_BEST);

    hipMemsetAsync(d_ws, 0, WS_ZERO_BYTES, stream);
    hipMemsetAsync(ws + WS_BEST, 0, WS_BEST_BYTES, stream);
    k_convert_cb<<<1024, 256, 0, stream>>>(cb, cbh, cbl);
    k_dist<<<NBLK, 256, 0, stream>>>(x, cbh, cbl, ws_best, ws_work);
    k_post<<<NROWS / 64, 256, 0, stream>>>(cb, gcb, ws_best,
                                           ws_scnt, ws_gsum, ws_gcnt, ws_rowcode, out);
    k_scan<<<1, 1024, 0, stream>>>(ws_scnt, ws_offs, ws_curs);
    k_scatter<<<(NROWS + 255) / 256, 256, 0, stream>>>(ws_rowcode, ws_curs, ws_bucket);
    k_reduce<<<KCB + 1, 256, 0, stream>>>(x, cb, gcb, snum, gnum,
                                          ws_scnt, ws_offs, ws_bucket,
                                          ws_gsum, ws_gcnt, out);
}

// Round 13
// 220.898 us; speedup vs baseline: 1.1303x; 1.1303x over previous
//
#include <hip/hip_runtime.h>
#include <math.h>
#include <stdint.h>

// ---------------- problem constants ----------------
#define NROWS 48000
#define DIM   256
#define KCB   1024
#define GK    64
#define TM    64      // rows per block in K1 (4 waves x 16 rows) -> grid 750
#define NCH   64      // chunks of 16 codes

// ---------------- workspace byte offsets ----------------
#define WS_SCNT    0u         // int[1024]
#define WS_GSUM    4096u      // float[64]
#define WS_GCNT    4352u      // float[64]
#define WS_OFFS    4608u      // int[1024]
#define WS_CURS    8704u      // int[1024]
#define WS_ROWCODE 12800u     // int[48000]
#define WS_BUCKET  204800u    // int[48000]
#define WS_CBHI    396800u    // _Float16[1024*256] swizzled (524288 B)
#define WS_CBLO    921088u    // _Float16[1024*256] swizzled (524288 B)
#define WS_ZERO_BYTES 4608u

// ---------------- output element offsets ----------------
#define OUT_SHAPE 12288000
#define OUT_GAIN  12550144
#define OUT_SNUM  12550208
#define OUT_GNUM  12551232

typedef _Float16 half8  __attribute__((ext_vector_type(8)));
typedef float    f32x4  __attribute__((ext_vector_type(4)));
typedef int      i32x4  __attribute__((ext_vector_type(4)));

typedef __attribute__((address_space(1))) void* gptr_t;
typedef __attribute__((address_space(3))) void* lptr_t;

// K0: split fp32 codebook into f16 hi/lo planes, pre-swizzled into a
// LANE-LINEAR fragment order so that global_load_lds (which writes LDS at
// wave-uniform-base + lane*16B) lands each lane's MFMA B-fragment exactly
// where the lane will ds_read it back (lane*16B within the fragment).
// dst(halfs) = ch*4096 + kk*512 + lane*8 + e, lane = lq*16 + lc,
// where code = ch*16+lc, k = kk*32 + lq*8 + e.
__global__ __launch_bounds__(256) void k_convert_cb(const float* __restrict__ cb,
                                                    _Float16* __restrict__ hi,
                                                    _Float16* __restrict__ lo) {
    int i = blockIdx.x * 256 + threadIdx.x;   // 262144 total
    float v = cb[i];
    int code = i >> 8, k = i & 255;
    int ch = code >> 4, lc = code & 15;
    int kk = k >> 5, lq = (k & 31) >> 3, e = k & 7;
    int lane = lq * 16 + lc;
    int dst = ch * 4096 + kk * 512 + lane * 8 + e;
    _Float16 h = (_Float16)v;
    hi[dst] = h;
    lo[dst] = (_Float16)(v - (float)h);
}

// K1: round-3 structure (best pipeline, 218.2us: 64 rows/block, grid 750,
// ~3 blocks/CU, fused gain-quant + stats + quantize epilogue — fused tail
// measured 113.6us vs 141.3us for every split variant) + the round-7
// A-fragment asm pin. Round 3 ran with VGPR=60 < the 64 statically needed
// for the A-fragments: the compiler was re-loading + re-converting x from
// cache on EVERY of the 64 chunks (the pathology whose fix bought -24% on
// k_dist in round 6->7). The opaque asm pin makes the fragments
// non-rematerializable. Rounds 11/12's cross-block finisher handshake is
// abandoned (2x container failures); every construct here appeared in a
// kernel that passed rounds 0-10.
__global__ __launch_bounds__(256, 3) void k_main(
    const float* __restrict__ x, const float* __restrict__ cb,
    const float* __restrict__ gcb,
    const _Float16* __restrict__ cbh, const _Float16* __restrict__ cbl,
    int* __restrict__ ws_scnt, float* __restrict__ ws_gsum,
    float* __restrict__ ws_gcnt, int* __restrict__ ws_rowcode,
    float* __restrict__ out_q) {
    __shared__ float gl[GK];
    __shared__ int   shInd[TM];
    __shared__ float shGq[TM];
    __shared__ float shLg[TM];
    __shared__ float shGs[GK];   // per-block gain log-sum bins
    __shared__ float shGc[GK];   // per-block gain count bins
    __shared__ alignas(16) _Float16 ldsB[2][2][4096];  // [buf][hi/lo][8 KB]

    const int tid = threadIdx.x;
    const int w = tid >> 6, lane = tid & 63;
    const int lc = lane & 15, lq = lane >> 4;
    const int row0 = blockIdx.x * TM;

    // ---- stage chunk 0 into LDS buf0 (issue DMA first, hide under A-convert)
    {
#pragma unroll
        for (int j = 0; j < 4; ++j) {
            int f = w * 4 + j;
            int plane = f >> 3, kk = f & 7;
            const char* srcb = plane ? (const char*)cbl : (const char*)cbh;
            const char* src = srcb + kk * 1024 + lane * 16;   // ch = 0
            __builtin_amdgcn_global_load_lds((gptr_t)src,
                                             (lptr_t)&ldsB[0][plane][kk * 512],
                                             16, 0, 0);
        }
    }

    if (tid < GK) {
        gl[tid] = gcb[tid];
        shGs[tid] = 0.0f;
        shGc[tid] = 0.0f;
    }

    // ---- load + convert A fragments: 16 rows per wave ----
    i32x4 afh[8], afl[8];
    {
        const float* rp = x + (long)(row0 + w * 16 + lc) * DIM + lq * 8;
#pragma unroll
        for (int kk = 0; kk < 8; ++kk) {
            float4 v0 = *(const float4*)(rp + kk * 32);
            float4 v1 = *(const float4*)(rp + kk * 32 + 4);
            _Float16 h0 = (_Float16)v0.x, h1 = (_Float16)v0.y,
                     h2 = (_Float16)v0.z, h3 = (_Float16)v0.w;
            _Float16 h4 = (_Float16)v1.x, h5 = (_Float16)v1.y,
                     h6 = (_Float16)v1.z, h7 = (_Float16)v1.w;
            half8 hh = (half8){h0, h1, h2, h3, h4, h5, h6, h7};
            half8 ll = (half8){(_Float16)(v0.x - (float)h0), (_Float16)(v0.y - (float)h1),
                               (_Float16)(v0.z - (float)h2), (_Float16)(v0.w - (float)h3),
                               (_Float16)(v1.x - (float)h4), (_Float16)(v1.y - (float)h5),
                               (_Float16)(v1.z - (float)h6), (_Float16)(v1.w - (float)h7)};
            afh[kk] = __builtin_bit_cast(i32x4, hh);
            afl[kk] = __builtin_bit_cast(i32x4, ll);
        }
    }

    // ---- PIN: opaque asm def keeps A-fragments register-resident ----
#pragma unroll
    for (int kk = 0; kk < 8; ++kk)
        asm volatile("" : "+v"(afh[kk]), "+v"(afl[kk]));

    float vmax[4];
    int   vidx[4];
#pragma unroll
    for (int r = 0; r < 4; ++r) { vmax[r] = -1e30f; vidx[r] = 0; }

    __syncthreads();   // drains vmcnt: buf0 staged; gl[] ready

    // ---- K-loop: 2-phase { stage(next) ; compute(cur) ; barrier } ----
    int cur = 0;
    for (int ch = 0; ch < NCH; ++ch) {
        if (ch + 1 < NCH) {
#pragma unroll
            for (int j = 0; j < 4; ++j) {
                int f = w * 4 + j;
                int plane = f >> 3, kk = f & 7;
                const char* srcb = plane ? (const char*)cbl : (const char*)cbh;
                const char* src = srcb + (size_t)(ch + 1) * 8192 + kk * 1024 + lane * 16;
                __builtin_amdgcn_global_load_lds((gptr_t)src,
                                                 (lptr_t)&ldsB[cur ^ 1][plane][kk * 512],
                                                 16, 0, 0);
            }
        }

        const _Float16* bH = &ldsB[cur][0][lane * 8];
        const _Float16* bL = &ldsB[cur][1][lane * 8];

        f32x4 a0 = (f32x4){0, 0, 0, 0};
        f32x4 a1 = (f32x4){0, 0, 0, 0};
        f32x4 a2 = (f32x4){0, 0, 0, 0};
#pragma unroll
        for (int kk = 0; kk < 8; ++kk) {
            half8 bh = *(const half8*)(bH + kk * 512);
            half8 bl = *(const half8*)(bL + kk * 512);
            half8 ah = __builtin_bit_cast(half8, afh[kk]);
            half8 al = __builtin_bit_cast(half8, afl[kk]);
            a0 = __builtin_amdgcn_mfma_f32_16x16x32_f16(ah, bh, a0, 0, 0, 0);
            a1 = __builtin_amdgcn_mfma_f32_16x16x32_f16(al, bh, a1, 0, 0, 0);
            a2 = __builtin_amdgcn_mfma_f32_16x16x32_f16(ah, bl, a2, 0, 0, 0);
        }
        int code = ch * 16 + lc;
#pragma unroll
        for (int r = 0; r < 4; ++r) {
            float dv = a0[r] + a1[r] + a2[r];
            if (dv > vmax[r]) { vmax[r] = dv; vidx[r] = code; }
        }

        __syncthreads();   // drains DMA for next buf; syncs buffer swap
        cur ^= 1;
    }

    // ---- argmax reduce across the 16-lane col (lc) dimension ----
#pragma unroll
    for (int m = 1; m < 16; m <<= 1) {
#pragma unroll
        for (int r = 0; r < 4; ++r) {
            float ov = __shfl_xor(vmax[r], m, 64);
            int   oi = __shfl_xor(vidx[r], m, 64);
            if (ov > vmax[r] || (ov == vmax[r] && oi < vidx[r])) {
                vmax[r] = ov; vidx[r] = oi;
            }
        }
    }
    if (lc == 0) {
#pragma unroll
        for (int r = 0; r < 4; ++r) {
            int lrow = w * 16 + lq * 4 + r;
            shLg[lrow]  = vmax[r];
            shInd[lrow] = vidx[r];
        }
    }
    __syncthreads();

    // ---- parallel gain quantization: lane j evaluates level j ----
    {
        float glv = gl[lane];
        for (int i = 0; i < 16; ++i) {
            int row = w * 16 + i;
            float gv = shLg[row];
            float lg = logf(fmaxf(gv, 1e-5f));
            float d = lg - glv; d = d * d;
            int gi = lane;
#pragma unroll
            for (int m = 1; m < 64; m <<= 1) {
                float od = __shfl_xor(d, m, 64);
                int   og = __shfl_xor(gi, m, 64);
                if (od < d || (od == d && og < gi)) { d = od; gi = og; }
            }
            if (lane == i) {
                float gsel = gl[gi];
                shGq[row] = expf(gsel);
                int sidx = shInd[row];
                ws_rowcode[row0 + row] = sidx;
                atomicAdd(ws_scnt + sidx, 1);
                atomicAdd(shGs + gi, lg);     // LDS pre-aggregation
                atomicAdd(shGc + gi, 1.0f);
            }
        }
    }
    __syncthreads();
    if (tid < GK) {
        if (shGc[tid] != 0.0f) {
            atomicAdd(ws_gsum + tid, shGs[tid]);
            atomicAdd(ws_gcnt + tid, shGc[tid]);
        }
    }

    // ---- epilogue: quantize = exp(gain_q) * cb[code] ----
    {
        float4* qv = (float4*)(out_q + (long)row0 * DIM);
#pragma unroll
        for (int it = 0; it < 16; ++it) {
            int idx = it * 256 + tid;       // 4096 float4s
            int r = idx >> 6, c4 = idx & 63;
            int code = shInd[r];
            float gq = shGq[r];
            const float4 cbv = *(const float4*)(cb + code * DIM + c4 * 4);
            float4 o;
            o.x = gq * cbv.x; o.y = gq * cbv.y; o.z = gq * cbv.z; o.w = gq * cbv.w;
            qv[idx] = o;
        }
    }
}

// K2a: exclusive prefix scan of code counts -> bucket offsets + cursors
__global__ __launch_bounds__(1024) void k_scan(const int* __restrict__ scnt,
                                               int* __restrict__ offs,
                                               int* __restrict__ curs) {
    int t = threadIdx.x;
    __shared__ int sc[1024];
    int my = scnt[t];
    sc[t] = my;
    __syncthreads();
    for (int d = 1; d < 1024; d <<= 1) {
        int v = (t >= d) ? sc[t - d] : 0;
        __syncthreads();
        sc[t] += v;
        __syncthreads();
    }
    int ex = sc[t] - my;
    offs[t] = ex;
    curs[t] = ex;
}

// K2b: scatter row ids into code-sorted buckets
__global__ __launch_bounds__(256) void k_scatter(const int* __restrict__ rowcode,
                                                 int* __restrict__ curs,
                                                 int* __restrict__ bucket) {
    int i = blockIdx.x * 256 + threadIdx.x;
    if (i < NROWS) {
        int code = rowcode[i];
        int pos = atomicAdd(curs + code, 1);
        bucket[pos] = i;
    }
}

// K2c: per-code column reduction of x + full shape/gain finalize
__global__ __launch_bounds__(256) void k_reduce(
    const float* __restrict__ x, const float* __restrict__ cb,
    const float* __restrict__ gcb, const float* __restrict__ snum,
    const float* __restrict__ gnum,
    const int* __restrict__ scnt, const int* __restrict__ offs,
    const int* __restrict__ bucket,
    const float* __restrict__ gsum, const float* __restrict__ gcnt,
    float* __restrict__ out) {
    int b = blockIdx.x, t = threadIdx.x;
    if (b < KCB) {
        int cnt = scnt[b], base = offs[b];
        float s = 0.0f;
        int i = 0;
        for (; i + 4 <= cnt; i += 4) {
            int r0 = bucket[base + i], r1 = bucket[base + i + 1];
            int r2 = bucket[base + i + 2], r3 = bucket[base + i + 3];
            float v0 = x[r0 * DIM + t], v1 = x[r1 * DIM + t];
            float v2 = x[r2 * DIM + t], v3 = x[r3 * DIM + t];
            s += v0 + v1 + v2 + v3;
        }
        for (; i < cnt; ++i) {
            int r = bucket[base + i];
            s += x[r * DIM + t];
        }
        __shared__ float red[4];
        int w = t >> 6;
        float v = s * s;
#pragma unroll
        for (int m = 32; m; m >>= 1) v += __shfl_xor(v, m, 64);
        if ((t & 63) == 0) red[w] = v;
        __syncthreads();
        float tot = red[0] + red[1] + red[2] + red[3];
        float sn = s / fmaxf(sqrtf(tot), 1e-5f);
        float u = cb[b * DIM + t] * 0.99f + 0.01f * sn;
        __syncthreads();
        v = u * u;
#pragma unroll
        for (int m = 32; m; m >>= 1) v += __shfl_xor(v, m, 64);
        if ((t & 63) == 0) red[w] = v;
        __syncthreads();
        tot = red[0] + red[1] + red[2] + red[3];
        out[OUT_SHAPE + b * DIM + t] = u / fmaxf(sqrtf(tot), 1e-12f);
        if (t == 0) out[OUT_SNUM + b] = snum[b] * 0.99f + 0.01f * (float)cnt;
    } else if (t < GK) {
        float cnt = gcnt[t];
        float gn  = gsum[t] / fmaxf(cnt, 1e-5f);
        out[OUT_GAIN + t] = gcb[t] * 0.99f + 0.01f * gn;
        out[OUT_GNUM + t] = gnum[t] * 0.99f + 0.01f * cnt;
    }
}

extern "C" void kernel_launch(void* const* d_in, const int* in_sizes, int n_in,
                              void* d_out, int out_size, void* d_ws, size_t ws_size,
                              hipStream_t stream) {
    const float* x    = (const float*)d_in[0];
    const float* cb   = (const float*)d_in[1];
    const float* gcb  = (const float*)d_in[2];
    const float* snum = (const float*)d_in[3];
    const float* gnum = (const float*)d_in[4];
    float* out = (float*)d_out;
    char*  ws  = (char*)d_ws;
    int*   ws_scnt    = (int*)(ws + WS_SCNT);
    float* ws_gsum    = (float*)(ws + WS_GSUM);
    float* ws_gcnt    = (float*)(ws + WS_GCNT);
    int*   ws_offs    = (int*)(ws + WS_OFFS);
    int*   ws_curs    = (int*)(ws + WS_CURS);
    int*   ws_rowcode = (int*)(ws + WS_ROWCODE);
    int*   ws_bucket  = (int*)(ws + WS_BUCKET);
    _Float16* cbh = (_Float16*)(ws + WS_CBHI);
    _Float16* cbl = (_Float16*)(ws + WS_CBLO);

    hipMemsetAsync(d_ws, 0, WS_ZERO_BYTES, stream);
    k_convert_cb<<<1024, 256, 0, stream>>>(cb, cbh, cbl);
    k_main<<<NROWS / TM, 256, 0, stream>>>(x, cb, gcb, cbh, cbl,
                                           ws_scnt, ws_gsum, ws_gcnt, ws_rowcode, out);
    k_scan<<<1, 1024, 0, stream>>>(ws_scnt, ws_offs, ws_curs);
    k_scatter<<<(NROWS + 255) / 256, 256, 0, stream>>>(ws_rowcode, ws_curs, ws_bucket);
    k_reduce<<<KCB + 1, 256, 0, stream>>>(x, cb, gcb, snum, gnum,
                                          ws_scnt, ws_offs, ws_bucket,
                                          ws_gsum, ws_gcnt, out);
}